// Round 1
// baseline (1244.500 us; speedup 1.0000x reference)
//
#include <hip/hip_runtime.h>
#include <stdint.h>

typedef unsigned short ushort_t;
typedef short v8s __attribute__((ext_vector_type(8)));
typedef float v4f __attribute__((ext_vector_type(4)));
typedef unsigned int uint32;

#define DIM   4096
#define NH    32
#define NKV   8
#define HD    128
#define SEQ   2048
#define BATCH 2
#define NTOK  (BATCH * SEQ)            // 4096 tokens
#define QKVN  (NH * HD + 2 * NKV * HD) // 6144 = 4096 Q + 1024 K + 1024 V
#define KOFF  (NH * HD)                // 4096
#define VOFF  (NH * HD + NKV * HD)     // 5120

__device__ __forceinline__ ushort_t f2bf(float f) {
    uint32 u = __float_as_uint(f);
    u += 0x7fff + ((u >> 16) & 1);   // RNE
    return (ushort_t)(u >> 16);
}
__device__ __forceinline__ float bf2f(ushort_t h) {
    return __uint_as_float(((uint32)h) << 16);
}
__device__ __forceinline__ void gl2lds16(const void* g, void* l) {
    __builtin_amdgcn_global_load_lds(
        (const __attribute__((address_space(1))) uint32*)g,
        (__attribute__((address_space(3))) uint32*)l, 16, 0, 0);
}

// ---------------- fp32 -> bf16 convert (vectorized) ----------------
__global__ void cvt_f32_bf16(const float* __restrict__ src,
                             ushort_t* __restrict__ dst, int n4) {
    int i = blockIdx.x * blockDim.x + threadIdx.x;
    if (i >= n4) return;
    float4 v = ((const float4*)src)[i];
    uint32 lo = ((uint32)f2bf(v.y) << 16) | f2bf(v.x);
    uint32 hi = ((uint32)f2bf(v.w) << 16) | f2bf(v.z);
    ((uint2*)dst)[i] = make_uint2(lo, hi);
}

// ---------------- GEMM: C[M,N] = A[M,K] * B[N,K]^T (bf16 in, f32 acc) -------
// 128x128 tile, 256 thr (4 waves, each 64x64), BK=32, global_load_lds staging.
template <int OUT_BF16>
__global__ __launch_bounds__(256) void gemm_bt(const ushort_t* __restrict__ A,
                                               const ushort_t* __restrict__ B,
                                               float* __restrict__ Cf,
                                               ushort_t* __restrict__ Cb,
                                               int M, int N, int K) {
    __shared__ ushort_t As[128 * 32];
    __shared__ ushort_t Bs[128 * 32];
    const int t = threadIdx.x;
    const int w = t >> 6, lane = t & 63;
    const int g8 = lane >> 4, l16 = lane & 15;
    const int wr = (w >> 1) * 64, wc = (w & 1) * 64;
    const int bm = blockIdx.x, bn = blockIdx.y;

    const ushort_t* Ab = A + (size_t)(bm * 128) * K;
    const ushort_t* Bb = B + (size_t)(bn * 128) * K;

    v4f acc[4][4];
    v4f z = {0.f, 0.f, 0.f, 0.f};
#pragma unroll
    for (int i = 0; i < 4; i++)
#pragma unroll
        for (int j = 0; j < 4; j++) acc[i][j] = z;

    for (int k0 = 0; k0 < K; k0 += 32) {
        __syncthreads();
#pragma unroll
        for (int i = 0; i < 2; ++i) {
            int c = i * 256 + t;             // 512 chunks of 8 bf16
            int r = c >> 2, col = (c & 3) << 3;
            gl2lds16(&Ab[(size_t)r * K + k0 + col], &As[c * 8]);
            gl2lds16(&Bb[(size_t)r * K + k0 + col], &Bs[c * 8]);
        }
        __syncthreads();
        v8s a[4], b[4];
#pragma unroll
        for (int i = 0; i < 4; i++)
            a[i] = *(const v8s*)&As[(wr + i * 16 + l16) * 32 + g8 * 8];
#pragma unroll
        for (int j = 0; j < 4; j++)
            b[j] = *(const v8s*)&Bs[(wc + j * 16 + l16) * 32 + g8 * 8];
#pragma unroll
        for (int i = 0; i < 4; i++)
#pragma unroll
            for (int j = 0; j < 4; j++)
                acc[i][j] = __builtin_amdgcn_mfma_f32_16x16x32_bf16(
                    a[i], b[j], acc[i][j], 0, 0, 0);
    }

    const int rowbase = bm * 128 + wr, colbase = bn * 128 + wc;
#pragma unroll
    for (int i = 0; i < 4; i++)
#pragma unroll
        for (int j = 0; j < 4; j++)
#pragma unroll
            for (int r = 0; r < 4; r++) {
                int row = rowbase + i * 16 + g8 * 4 + r;
                int col = colbase + j * 16 + l16;
                float v = acc[i][j][r];
                if (OUT_BF16)
                    Cb[(size_t)row * N + col] = f2bf(v);
                else
                    Cf[(size_t)row * N + col] = v;
            }
}

// ---------------- RoPE + reorg: qkv[tok][6144] -> Q[b,h,s,d], K[b,g,s,d] ----
__global__ __launch_bounds__(256) void rope_reorg(const ushort_t* __restrict__ qkv,
                                                  const float* __restrict__ fc,
                                                  const float* __restrict__ fs,
                                                  ushort_t* __restrict__ Qo,
                                                  ushort_t* __restrict__ Ko) {
    const int tok = blockIdx.x;
    const int bb = tok >> 11, s = tok & 2047;
    const ushort_t* base = qkv + (size_t)tok * QKVN;
    const int t = threadIdx.x;
    const float qscale = 0.08838834764831845f;  // 1/sqrt(128)
    uint32* Qw = (uint32*)Qo;
    uint32* Kw = (uint32*)Ko;
    // Q: 32 heads * 64 pairs = 2048 pairs
#pragma unroll
    for (int i = 0; i < 8; ++i) {
        int p = i * 256 + t;
        int hh = p >> 6, pi = p & 63;
        float c = fc[s * 64 + pi], sn = fs[s * 64 + pi];
        uint32 u = *(const uint32*)&base[hh * 128 + 2 * pi];
        float t0 = bf2f((ushort_t)(u & 0xffff));
        float t1 = bf2f((ushort_t)(u >> 16));
        float o0 = (t0 * c - t1 * sn) * qscale;
        float o1 = (t0 * sn + t1 * c) * qscale;
        size_t dst = (((size_t)bb * NH + hh) * SEQ + s) * HD + 2 * pi;
        Qw[dst >> 1] = ((uint32)f2bf(o1) << 16) | f2bf(o0);
    }
    // K: 8 heads * 64 pairs = 512 pairs
#pragma unroll
    for (int i = 0; i < 2; ++i) {
        int p = i * 256 + t;
        int hh = p >> 6, pi = p & 63;
        float c = fc[s * 64 + pi], sn = fs[s * 64 + pi];
        uint32 u = *(const uint32*)&base[KOFF + hh * 128 + 2 * pi];
        float t0 = bf2f((ushort_t)(u & 0xffff));
        float t1 = bf2f((ushort_t)(u >> 16));
        float o0 = t0 * c - t1 * sn;
        float o1 = t0 * sn + t1 * c;
        size_t dst = (((size_t)bb * NKV + hh) * SEQ + s) * HD + 2 * pi;
        Kw[dst >> 1] = ((uint32)f2bf(o1) << 16) | f2bf(o0);
    }
}

// ---------------- V transpose: qkv V slice -> Vt[b,g,d,s] -------------------
__global__ __launch_bounds__(256) void v_transpose(const ushort_t* __restrict__ qkv,
                                                   ushort_t* __restrict__ Vt) {
    __shared__ ushort_t tile[64][136];  // padded: col-reads spread banks
    const int st = blockIdx.x, kvh = blockIdx.y, bb = blockIdx.z;
    const int t = threadIdx.x;
    const int s0 = st * 64;
#pragma unroll
    for (int i = 0; i < 4; ++i) {
        int c = i * 256 + t;                 // 1024 chunks of 8
        int r = c >> 4, col8 = (c & 15) * 8;
        int tok = (bb << 11) + s0 + r;
        *(v8s*)&tile[r][col8] =
            *(const v8s*)&qkv[(size_t)tok * QKVN + VOFF + kvh * 128 + col8];
    }
    __syncthreads();
#pragma unroll
    for (int i = 0; i < 4; ++i) {
        int c = i * 256 + t;                 // 1024 chunks: d rows x 8 s
        int d = c >> 3, s8 = (c & 7) * 8;
        ushort_t tmp[8];
#pragma unroll
        for (int j = 0; j < 8; j++) tmp[j] = tile[s8 + j][d];
        *(v8s*)&Vt[(((size_t)bb * NKV + kvh) * HD + d) * SEQ + s0 + s8] =
            *(v8s*)tmp;
    }
}

// ---------------- Flash attention (causal, GQA) -----------------------------
// grid (32 q-tiles, 32 heads, 2 batch), 256 thr. Wave w: 16 q-rows.
__global__ __launch_bounds__(256) void attn_kernel(const ushort_t* __restrict__ Q,
                                                   const ushort_t* __restrict__ Kc,
                                                   const ushort_t* __restrict__ Vt,
                                                   ushort_t* __restrict__ Out) {
    __shared__ ushort_t Ks[64 * 128];      // K tile [s_k][d]
    __shared__ ushort_t Vs[128 * 64];      // Vt tile [d][s_k]
    __shared__ ushort_t Ps[4][16 * 64];    // per-wave P tile
    const int qt = blockIdx.x, h = blockIdx.y, bb = blockIdx.z;
    const int kvh = h >> 2;
    const int t = threadIdx.x, w = t >> 6, lane = t & 63;
    const int g8 = lane >> 4, l16 = lane & 15;
    const int q0 = qt * 64;
    const int qrow_base = q0 + w * 16;

    // preload Q fragments (Q pre-scaled by 1/sqrt(128))
    const size_t qbase = (((size_t)bb * NH + h) * SEQ + qrow_base) * HD;
    v8s qf[4];
#pragma unroll
    for (int ks = 0; ks < 4; ++ks)
        qf[ks] = *(const v8s*)&Q[qbase + (size_t)l16 * HD + ks * 32 + g8 * 8];

    float m_i[4], l_i[4];
#pragma unroll
    for (int r = 0; r < 4; r++) { m_i[r] = -1e30f; l_i[r] = 0.f; }
    v4f z = {0.f, 0.f, 0.f, 0.f};
    v4f o[8];
#pragma unroll
    for (int n = 0; n < 8; n++) o[n] = z;

    const ushort_t* Kbase = Kc + ((size_t)bb * NKV + kvh) * SEQ * HD;
    const ushort_t* Vbase = Vt + ((size_t)bb * NKV + kvh) * HD * SEQ;
    ushort_t* Pw = &Ps[w][0];

    for (int kt = 0; kt <= qt; ++kt) {
        __syncthreads();
        const ushort_t* Kt = Kbase + (size_t)kt * 64 * HD;  // contiguous 16KB
#pragma unroll
        for (int i = 0; i < 4; ++i) {
            int c = i * 256 + t;
            gl2lds16(&Kt[c * 8], &Ks[c * 8]);
        }
#pragma unroll
        for (int i = 0; i < 4; ++i) {
            int c = i * 256 + t;
            int d = c >> 3, s8 = (c & 7) * 8;
            gl2lds16(&Vbase[(size_t)d * SEQ + kt * 64 + s8], &Vs[c * 8]);
        }
        __syncthreads();

        // S = Q K^T : 4 column tiles of 16
        v4f s[4];
#pragma unroll
        for (int j = 0; j < 4; j++) s[j] = z;
#pragma unroll
        for (int j = 0; j < 4; j++)
#pragma unroll
            for (int ks = 0; ks < 4; ks++) {
                v8s kb = *(const v8s*)&Ks[(j * 16 + l16) * 128 + ks * 32 + g8 * 8];
                s[j] = __builtin_amdgcn_mfma_f32_16x16x32_bf16(qf[ks], kb, s[j], 0, 0, 0);
            }

        if (kt == qt) {  // causal mask on diagonal tile
#pragma unroll
            for (int j = 0; j < 4; j++) {
                int col = kt * 64 + j * 16 + l16;
#pragma unroll
                for (int r = 0; r < 4; r++) {
                    int row = qrow_base + g8 * 4 + r;
                    if (col > row) s[j][r] = -1e30f;
                }
            }
        }

        // online softmax: row stats over 64 cols (4 reg-tiles x 16 lanes)
        float alpha[4];
#pragma unroll
        for (int r = 0; r < 4; r++) {
            float v = fmaxf(fmaxf(s[0][r], s[1][r]), fmaxf(s[2][r], s[3][r]));
#pragma unroll
            for (int off = 1; off < 16; off <<= 1) v = fmaxf(v, __shfl_xor(v, off, 64));
            float mnew = fmaxf(m_i[r], v);
            alpha[r] = __expf(m_i[r] - mnew);
            m_i[r] = mnew;
        }
        float rs[4] = {0.f, 0.f, 0.f, 0.f};
#pragma unroll
        for (int j = 0; j < 4; j++)
#pragma unroll
            for (int r = 0; r < 4; r++) {
                float p = __expf(s[j][r] - m_i[r]);
                s[j][r] = p;
                rs[r] += p;
            }
#pragma unroll
        for (int r = 0; r < 4; r++) {
            float v = rs[r];
#pragma unroll
            for (int off = 1; off < 16; off <<= 1) v += __shfl_xor(v, off, 64);
            l_i[r] = l_i[r] * alpha[r] + v;
        }

        // P -> LDS (C-layout -> A-layout round trip), rescale O
#pragma unroll
        for (int j = 0; j < 4; j++)
#pragma unroll
            for (int r = 0; r < 4; r++)
                Pw[(g8 * 4 + r) * 64 + j * 16 + l16] = f2bf(s[j][r]);
#pragma unroll
        for (int n = 0; n < 8; n++)
#pragma unroll
            for (int r = 0; r < 4; r++) o[n][r] *= alpha[r];
        __syncthreads();

        // O += P V : A = P[16 x 64], B^T = Vt[d][s_k]
#pragma unroll
        for (int ks = 0; ks < 2; ++ks) {
            v8s pa = *(const v8s*)&Pw[l16 * 64 + ks * 32 + g8 * 8];
#pragma unroll
            for (int n = 0; n < 8; n++) {
                v8s vb = *(const v8s*)&Vs[(n * 16 + l16) * 64 + ks * 32 + g8 * 8];
                o[n] = __builtin_amdgcn_mfma_f32_16x16x32_bf16(pa, vb, o[n], 0, 0, 0);
            }
        }
    }

    // epilogue: Out[b][s][h][d], divide by l
#pragma unroll
    for (int n = 0; n < 8; n++)
#pragma unroll
        for (int r = 0; r < 4; r++) {
            int row = qrow_base + g8 * 4 + r;
            int col = n * 16 + l16;
            float val = o[n][r] / l_i[r];
            Out[(((size_t)bb * SEQ + row) * NH + h) * HD + col] = f2bf(val);
        }
}

// ---------------- launch ----------------------------------------------------
extern "C" void kernel_launch(void* const* d_in, const int* in_sizes, int n_in,
                              void* d_out, int out_size, void* d_ws, size_t ws_size,
                              hipStream_t stream) {
    const float* x  = (const float*)d_in[0];
    const float* wq = (const float*)d_in[1];
    const float* wk = (const float*)d_in[2];
    const float* wv = (const float*)d_in[3];
    const float* wo = (const float*)d_in[4];
    const float* fc = (const float*)d_in[5];
    const float* fs = (const float*)d_in[6];
    float* out = (float*)d_out;

    ushort_t* ws = (ushort_t*)d_ws;
    size_t off = 0;
    ushort_t* xb    = ws + off; off += (size_t)NTOK * DIM;   // reused as attn_out
    ushort_t* wqkvb = ws + off; off += (size_t)QKVN * DIM;
    ushort_t* wob   = ws + off; off += (size_t)DIM * DIM;
    ushort_t* qkv   = ws + off; off += (size_t)NTOK * QKVN;
    ushort_t* Qb    = ws + off; off += (size_t)BATCH * NH * SEQ * HD;
    ushort_t* Kb    = ws + off; off += (size_t)BATCH * NKV * SEQ * HD;
    ushort_t* Vt    = ws + off; off += (size_t)BATCH * NKV * HD * SEQ;
    ushort_t* attn_out = xb;  // x dead after QKV GEMM

    // converts
    cvt_f32_bf16<<<(NTOK * DIM / 4) / 256, 256, 0, stream>>>(x, xb, NTOK * DIM / 4);
    cvt_f32_bf16<<<(DIM * DIM / 4) / 256, 256, 0, stream>>>(wq, wqkvb, DIM * DIM / 4);
    cvt_f32_bf16<<<(NKV * HD * DIM / 4) / 256, 256, 0, stream>>>(
        wk, wqkvb + (size_t)KOFF * DIM, NKV * HD * DIM / 4);
    cvt_f32_bf16<<<(NKV * HD * DIM / 4) / 256, 256, 0, stream>>>(
        wv, wqkvb + (size_t)VOFF * DIM, NKV * HD * DIM / 4);
    cvt_f32_bf16<<<(DIM * DIM / 4) / 256, 256, 0, stream>>>(wo, wob, DIM * DIM / 4);

    // QKV projection
    dim3 g1(NTOK / 128, QKVN / 128);
    gemm_bt<1><<<g1, 256, 0, stream>>>(xb, wqkvb, nullptr, qkv, NTOK, QKVN, DIM);

    // RoPE + layout
    rope_reorg<<<NTOK, 256, 0, stream>>>(qkv, fc, fs, Qb, Kb);
    dim3 gv(SEQ / 64, NKV, BATCH);
    v_transpose<<<gv, 256, 0, stream>>>(qkv, Vt);

    // attention
    dim3 ga(SEQ / 64, NH, BATCH);
    attn_kernel<<<ga, 256, 0, stream>>>(Qb, Kb, Vt, attn_out);

    // output projection
    dim3 g2(NTOK / 128, DIM / 128);
    gemm_bt<0><<<g2, 256, 0, stream>>>(attn_out, wob, out, nullptr, NTOK, DIM, DIM);
}

// Round 2
// 1138.567 us; speedup vs baseline: 1.0930x; 1.0930x over previous
//
#include <hip/hip_runtime.h>
#include <stdint.h>

typedef unsigned short ushort_t;
typedef short v8s __attribute__((ext_vector_type(8)));
typedef float v4f __attribute__((ext_vector_type(4)));
typedef unsigned int uint32;

#define DIM   4096
#define NH    32
#define NKV   8
#define HD    128
#define SEQ   2048
#define BATCH 2
#define NTOK  (BATCH * SEQ)            // 4096 tokens
#define QKVN  (NH * HD + 2 * NKV * HD) // 6144 = 4096 Q + 1024 K + 1024 V
#define KOFF  (NH * HD)                // 4096
#define VOFF  (NH * HD + NKV * HD)     // 5120

__device__ __forceinline__ ushort_t f2bf(float f) {
    uint32 u = __float_as_uint(f);
    u += 0x7fff + ((u >> 16) & 1);   // RNE
    return (ushort_t)(u >> 16);
}
__device__ __forceinline__ float bf2f(ushort_t h) {
    return __uint_as_float(((uint32)h) << 16);
}
__device__ __forceinline__ void gl2lds16(const void* g, void* l) {
    __builtin_amdgcn_global_load_lds(
        (const __attribute__((address_space(1))) uint32*)g,
        (__attribute__((address_space(3))) uint32*)l, 16, 0, 0);
}
#if __has_builtin(__builtin_amdgcn_exp2f)
__device__ __forceinline__ float fast_exp2(float x) { return __builtin_amdgcn_exp2f(x); }
#else
__device__ __forceinline__ float fast_exp2(float x) { return exp2f(x); }
#endif

// ---------------- fp32 -> bf16 convert (vectorized) ----------------
__global__ void cvt_f32_bf16(const float* __restrict__ src,
                             ushort_t* __restrict__ dst, int n4) {
    int i = blockIdx.x * blockDim.x + threadIdx.x;
    if (i >= n4) return;
    float4 v = ((const float4*)src)[i];
    uint32 lo = ((uint32)f2bf(v.y) << 16) | f2bf(v.x);
    uint32 hi = ((uint32)f2bf(v.w) << 16) | f2bf(v.z);
    ((uint2*)dst)[i] = make_uint2(lo, hi);
}

// ---------------- GEMM: C[M,N] = A[M,K] * B[N,K]^T (bf16 in, f32 acc) -------
// 128x128 tile, 256 thr (4 waves, each 64x64), BK=32, global_load_lds staging.
// LDS chunk swizzle: logical (r, cc) [cc = 16B chunk in row, 4/row] stored at
// physical chunk (r>>1)*8 + ((((r&1)<<2)|cc) ^ ((r>>1)&7)) — spreads the
// 16-lane read slice over all 8 bank quads (2-way = free).
template <int OUT_BF16>
__global__ __launch_bounds__(256) void gemm_bt(const ushort_t* __restrict__ A,
                                               const ushort_t* __restrict__ B,
                                               float* __restrict__ Cf,
                                               ushort_t* __restrict__ Cb,
                                               int M, int N, int K) {
    __shared__ ushort_t As[128 * 32];
    __shared__ ushort_t Bs[128 * 32];
    const int t = threadIdx.x;
    const int w = t >> 6, lane = t & 63;
    const int g8 = lane >> 4, l16 = lane & 15;
    const int wr = (w >> 1) * 64, wc = (w & 1) * 64;
    const int bm = blockIdx.x, bn = blockIdx.y;

    const ushort_t* Ab = A + (size_t)(bm * 128) * K;
    const ushort_t* Bb = B + (size_t)(bn * 128) * K;

    v4f acc[4][4];
    v4f z = {0.f, 0.f, 0.f, 0.f};
#pragma unroll
    for (int i = 0; i < 4; i++)
#pragma unroll
        for (int j = 0; j < 4; j++) acc[i][j] = z;

    for (int k0 = 0; k0 < K; k0 += 32) {
        __syncthreads();
#pragma unroll
        for (int i = 0; i < 2; ++i) {
            int c = i * 256 + t;             // physical chunk 0..511
            int p = c >> 3, low = c & 7;
            int l7 = low ^ (p & 7);
            int r = p * 2 + (l7 >> 2);
            int cc = l7 & 3;
            gl2lds16(&Ab[(size_t)r * K + k0 + cc * 8], &As[c * 8]);
            gl2lds16(&Bb[(size_t)r * K + k0 + cc * 8], &Bs[c * 8]);
        }
        __syncthreads();
        v8s a[4], b[4];
#pragma unroll
        for (int i = 0; i < 4; i++) {
            int R = wr + i * 16 + l16;
            int pc = (R >> 1) * 8 + ((((R & 1) << 2) | g8) ^ ((R >> 1) & 7));
            a[i] = *(const v8s*)&As[pc * 8];
        }
#pragma unroll
        for (int j = 0; j < 4; j++) {
            int R = wc + j * 16 + l16;
            int pc = (R >> 1) * 8 + ((((R & 1) << 2) | g8) ^ ((R >> 1) & 7));
            b[j] = *(const v8s*)&Bs[pc * 8];
        }
#pragma unroll
        for (int i = 0; i < 4; i++)
#pragma unroll
            for (int j = 0; j < 4; j++)
                acc[i][j] = __builtin_amdgcn_mfma_f32_16x16x32_bf16(
                    a[i], b[j], acc[i][j], 0, 0, 0);
    }

    const int rowbase = bm * 128 + wr, colbase = bn * 128 + wc;
#pragma unroll
    for (int i = 0; i < 4; i++)
#pragma unroll
        for (int j = 0; j < 4; j++)
#pragma unroll
            for (int r = 0; r < 4; r++) {
                int row = rowbase + i * 16 + g8 * 4 + r;
                int col = colbase + j * 16 + l16;
                float v = acc[i][j][r];
                if (OUT_BF16)
                    Cb[(size_t)row * N + col] = f2bf(v);
                else
                    Cf[(size_t)row * N + col] = v;
            }
}

// ---------------- RoPE + reorg: qkv[tok][6144] -> Q[b,h,s,d], K[b,g,s,d] ----
// Q pre-scaled by (1/sqrt(HD)) * log2(e) so attention softmax runs in exp2
// domain (saves a v_mul per score element).
__global__ __launch_bounds__(256) void rope_reorg(const ushort_t* __restrict__ qkv,
                                                  const float* __restrict__ fc,
                                                  const float* __restrict__ fs,
                                                  ushort_t* __restrict__ Qo,
                                                  ushort_t* __restrict__ Ko) {
    const int tok = blockIdx.x;
    const int bb = tok >> 11, s = tok & 2047;
    const ushort_t* base = qkv + (size_t)tok * QKVN;
    const int t = threadIdx.x;
    const float qscale = 0.08838834764831845f * 1.4426950408889634f;
    uint32* Qw = (uint32*)Qo;
    uint32* Kw = (uint32*)Ko;
#pragma unroll
    for (int i = 0; i < 8; ++i) {
        int p = i * 256 + t;
        int hh = p >> 6, pi = p & 63;
        float c = fc[s * 64 + pi], sn = fs[s * 64 + pi];
        uint32 u = *(const uint32*)&base[hh * 128 + 2 * pi];
        float t0 = bf2f((ushort_t)(u & 0xffff));
        float t1 = bf2f((ushort_t)(u >> 16));
        float o0 = (t0 * c - t1 * sn) * qscale;
        float o1 = (t0 * sn + t1 * c) * qscale;
        size_t dst = (((size_t)bb * NH + hh) * SEQ + s) * HD + 2 * pi;
        Qw[dst >> 1] = ((uint32)f2bf(o1) << 16) | f2bf(o0);
    }
#pragma unroll
    for (int i = 0; i < 2; ++i) {
        int p = i * 256 + t;
        int hh = p >> 6, pi = p & 63;
        float c = fc[s * 64 + pi], sn = fs[s * 64 + pi];
        uint32 u = *(const uint32*)&base[KOFF + hh * 128 + 2 * pi];
        float t0 = bf2f((ushort_t)(u & 0xffff));
        float t1 = bf2f((ushort_t)(u >> 16));
        float o0 = t0 * c - t1 * sn;
        float o1 = t0 * sn + t1 * c;
        size_t dst = (((size_t)bb * NKV + hh) * SEQ + s) * HD + 2 * pi;
        Kw[dst >> 1] = ((uint32)f2bf(o1) << 16) | f2bf(o0);
    }
}

// ---------------- V transpose: qkv V slice -> Vt[b,g,d,s] -------------------
__global__ __launch_bounds__(256) void v_transpose(const ushort_t* __restrict__ qkv,
                                                   ushort_t* __restrict__ Vt) {
    __shared__ ushort_t tile[64][136];
    const int st = blockIdx.x, kvh = blockIdx.y, bb = blockIdx.z;
    const int t = threadIdx.x;
    const int s0 = st * 64;
#pragma unroll
    for (int i = 0; i < 4; ++i) {
        int c = i * 256 + t;
        int r = c >> 4, col8 = (c & 15) * 8;
        int tok = (bb << 11) + s0 + r;
        *(v8s*)&tile[r][col8] =
            *(const v8s*)&qkv[(size_t)tok * QKVN + VOFF + kvh * 128 + col8];
    }
    __syncthreads();
#pragma unroll
    for (int i = 0; i < 4; ++i) {
        int c = i * 256 + t;
        int d = c >> 3, s8 = (c & 7) * 8;
        ushort_t tmp[8];
#pragma unroll
        for (int j = 0; j < 8; j++) tmp[j] = tile[s8 + j][d];
        *(v8s*)&Vt[(((size_t)bb * NKV + kvh) * HD + d) * SEQ + s0 + s8] =
            *(v8s*)tmp;
    }
}

// ---------------- Flash attention (causal, GQA) -----------------------------
// Block: 128 q-rows, 4 waves; wave w owns 16-row tiles w and w+4 (interleaved
// for causal balance). 64-key tiles, XOR-swizzled K/V LDS (conflict-free).
// Scores are in exp2 domain (log2e folded into Q).
__device__ __forceinline__ void attn_tile(const v8s* qf, float* m_i, float* l_i,
                                          v4f* o, const ushort_t* Ks,
                                          const ushort_t* Vs, ushort_t* Pt,
                                          int k0, int Rbase, int g8, int l16) {
    v4f z = {0.f, 0.f, 0.f, 0.f};
    v4f s[4];
#pragma unroll
    for (int j = 0; j < 4; j++) s[j] = z;
#pragma unroll
    for (int j = 0; j < 4; j++)
#pragma unroll
        for (int ks = 0; ks < 4; ks++) {
            // K row R=j*16+l16 (R&15==l16), chunk cc=ks*4+g8, phys = R*16+(cc^l16)
            const v8s kb = *(const v8s*)&Ks[((j * 16 + l16) * 16 + ((ks * 4 + g8) ^ l16)) * 8];
            s[j] = __builtin_amdgcn_mfma_f32_16x16x32_bf16(qf[ks], kb, s[j], 0, 0, 0);
        }

    if (k0 + 63 > Rbase) {  // diagonal straddle: causal mask
#pragma unroll
        for (int j = 0; j < 4; j++) {
            int col = k0 + j * 16 + l16;
#pragma unroll
            for (int r = 0; r < 4; r++) {
                int row = Rbase + g8 * 4 + r;
                if (col > row) s[j][r] = -1e30f;
            }
        }
    }

    float alpha[4];
#pragma unroll
    for (int r = 0; r < 4; r++) {
        float v = fmaxf(fmaxf(s[0][r], s[1][r]), fmaxf(s[2][r], s[3][r]));
#pragma unroll
        for (int off = 1; off < 16; off <<= 1) v = fmaxf(v, __shfl_xor(v, off, 64));
        float mnew = fmaxf(m_i[r], v);
        alpha[r] = fast_exp2(m_i[r] - mnew);
        m_i[r] = mnew;
    }
    float rs[4] = {0.f, 0.f, 0.f, 0.f};
#pragma unroll
    for (int j = 0; j < 4; j++)
#pragma unroll
        for (int r = 0; r < 4; r++) {
            float p = fast_exp2(s[j][r] - m_i[r]);
            s[j][r] = p;
            rs[r] += p;
        }
#pragma unroll
    for (int r = 0; r < 4; r++) {
        float v = rs[r];
#pragma unroll
        for (int off = 1; off < 16; off <<= 1) v += __shfl_xor(v, off, 64);
        l_i[r] = l_i[r] * alpha[r] + v;
    }

    // P -> LDS (C-layout -> A-layout), stride 72 (pad kills write conflicts)
#pragma unroll
    for (int j = 0; j < 4; j++)
#pragma unroll
        for (int r = 0; r < 4; r++)
            Pt[(g8 * 4 + r) * 72 + j * 16 + l16] = f2bf(s[j][r]);
#pragma unroll
    for (int n = 0; n < 8; n++)
#pragma unroll
        for (int r = 0; r < 4; r++) o[n][r] *= alpha[r];

#pragma unroll
    for (int ks = 0; ks < 2; ++ks) {
        const v8s pa = *(const v8s*)&Pt[l16 * 72 + ks * 32 + g8 * 8];
#pragma unroll
        for (int n = 0; n < 8; n++) {
            // V row d=n*16+l16 (d&7==l16&7), chunk cc=ks*4+g8, phys = d*8+(cc^(d&7))
            const int d = n * 16 + l16;
            const v8s vb = *(const v8s*)&Vs[(d * 8 + ((ks * 4 + g8) ^ (l16 & 7))) * 8];
            o[n] = __builtin_amdgcn_mfma_f32_16x16x32_bf16(pa, vb, o[n], 0, 0, 0);
        }
    }
}

__global__ __launch_bounds__(256) void attn_kernel(const ushort_t* __restrict__ Q,
                                                   const ushort_t* __restrict__ Kc,
                                                   const ushort_t* __restrict__ Vt,
                                                   ushort_t* __restrict__ Out) {
    __shared__ ushort_t Ks[64 * 128];      // swizzled K tile
    __shared__ ushort_t Vs[128 * 64];      // swizzled Vt tile
    __shared__ ushort_t Ps[4][32 * 72];    // per-wave P (rows: tile0 0-15, tile1 16-31)
    const int qtb = gridDim.x - 1 - blockIdx.x;  // heavy blocks first
    const int h = blockIdx.y, bb = blockIdx.z;
    const int kvh = h >> 2;
    const int t = threadIdx.x, w = t >> 6, lane = t & 63;
    const int g8 = lane >> 4, l16 = lane & 15;
    const int q0 = qtb * 128;
    const int R0 = q0 + w * 16;       // row-tile 0 base (rows q0 .. q0+63)
    const int R1 = q0 + 64 + w * 16;  // row-tile 1 base (rows q0+64 .. q0+127)

    const size_t qb0 = (((size_t)bb * NH + h) * SEQ + R0) * HD;
    const size_t qb1 = (((size_t)bb * NH + h) * SEQ + R1) * HD;
    v8s qf0[4], qf1[4];
#pragma unroll
    for (int ks = 0; ks < 4; ++ks) {
        qf0[ks] = *(const v8s*)&Q[qb0 + (size_t)l16 * HD + ks * 32 + g8 * 8];
        qf1[ks] = *(const v8s*)&Q[qb1 + (size_t)l16 * HD + ks * 32 + g8 * 8];
    }

    float m0[4], l0[4], m1[4], l1[4];
#pragma unroll
    for (int r = 0; r < 4; r++) { m0[r] = -1e30f; l0[r] = 0.f; m1[r] = -1e30f; l1[r] = 0.f; }
    v4f z = {0.f, 0.f, 0.f, 0.f};
    v4f o0[8], o1[8];
#pragma unroll
    for (int n = 0; n < 8; n++) { o0[n] = z; o1[n] = z; }

    const ushort_t* Kbase = Kc + ((size_t)bb * NKV + kvh) * SEQ * HD;
    const ushort_t* Vbase = Vt + ((size_t)bb * NKV + kvh) * HD * SEQ;
    ushort_t* Pw = &Ps[w][0];

    const int nkt = 2 * qtb + 2;
    for (int kt = 0; kt < nkt; ++kt) {
        const int k0 = kt * 64;
        __syncthreads();
        const ushort_t* Kt = Kbase + (size_t)k0 * HD;
#pragma unroll
        for (int i = 0; i < 4; ++i) {   // K: 64 rows x 16 chunks, swizzled
            int c = i * 256 + t;
            int r = c >> 4, cc = (c & 15) ^ (r & 15);
            gl2lds16(&Kt[r * 128 + cc * 8], &Ks[c * 8]);
        }
#pragma unroll
        for (int i = 0; i < 4; ++i) {   // V: 128 d-rows x 8 chunks, swizzled
            int c = i * 256 + t;
            int d = c >> 3, cc = (c & 7) ^ (d & 7);
            gl2lds16(&Vbase[(size_t)d * SEQ + k0 + cc * 8], &Vs[c * 8]);
        }
        __syncthreads();

        attn_tile(qf1, m1, l1, o1, Ks, Vs, Pw + 16 * 72, k0, R1, g8, l16);
        if (kt < nkt - 1)  // row-tile 0 fully masked only on the last kt
            attn_tile(qf0, m0, l0, o0, Ks, Vs, Pw, k0, R0, g8, l16);
    }

    // epilogue: Out[b][s][h][d], divide by l
#pragma unroll
    for (int n = 0; n < 8; n++)
#pragma unroll
        for (int r = 0; r < 4; r++) {
            int col = n * 16 + l16;
            int row0 = R0 + g8 * 4 + r;
            int row1 = R1 + g8 * 4 + r;
            Out[(((size_t)bb * SEQ + row0) * NH + h) * HD + col] = f2bf(o0[n][r] / l0[r]);
            Out[(((size_t)bb * SEQ + row1) * NH + h) * HD + col] = f2bf(o1[n][r] / l1[r]);
        }
}

// ---------------- launch ----------------------------------------------------
extern "C" void kernel_launch(void* const* d_in, const int* in_sizes, int n_in,
                              void* d_out, int out_size, void* d_ws, size_t ws_size,
                              hipStream_t stream) {
    const float* x  = (const float*)d_in[0];
    const float* wq = (const float*)d_in[1];
    const float* wk = (const float*)d_in[2];
    const float* wv = (const float*)d_in[3];
    const float* wo = (const float*)d_in[4];
    const float* fc = (const float*)d_in[5];
    const float* fs = (const float*)d_in[6];
    float* out = (float*)d_out;

    ushort_t* ws = (ushort_t*)d_ws;
    size_t off = 0;
    ushort_t* xb    = ws + off; off += (size_t)NTOK * DIM;   // reused as attn_out
    ushort_t* wqkvb = ws + off; off += (size_t)QKVN * DIM;
    ushort_t* wob   = ws + off; off += (size_t)DIM * DIM;
    ushort_t* qkv   = ws + off; off += (size_t)NTOK * QKVN;
    ushort_t* Qb    = ws + off; off += (size_t)BATCH * NH * SEQ * HD;
    ushort_t* Kb    = ws + off; off += (size_t)BATCH * NKV * SEQ * HD;
    ushort_t* Vt    = ws + off; off += (size_t)BATCH * NKV * HD * SEQ;
    ushort_t* attn_out = xb;  // x dead after QKV GEMM

    cvt_f32_bf16<<<(NTOK * DIM / 4) / 256, 256, 0, stream>>>(x, xb, NTOK * DIM / 4);
    cvt_f32_bf16<<<(DIM * DIM / 4) / 256, 256, 0, stream>>>(wq, wqkvb, DIM * DIM / 4);
    cvt_f32_bf16<<<(NKV * HD * DIM / 4) / 256, 256, 0, stream>>>(
        wk, wqkvb + (size_t)KOFF * DIM, NKV * HD * DIM / 4);
    cvt_f32_bf16<<<(NKV * HD * DIM / 4) / 256, 256, 0, stream>>>(
        wv, wqkvb + (size_t)VOFF * DIM, NKV * HD * DIM / 4);
    cvt_f32_bf16<<<(DIM * DIM / 4) / 256, 256, 0, stream>>>(wo, wob, DIM * DIM / 4);

    dim3 g1(NTOK / 128, QKVN / 128);
    gemm_bt<1><<<g1, 256, 0, stream>>>(xb, wqkvb, nullptr, qkv, NTOK, QKVN, DIM);

    rope_reorg<<<NTOK, 256, 0, stream>>>(qkv, fc, fs, Qb, Kb);
    dim3 gv(SEQ / 64, NKV, BATCH);
    v_transpose<<<gv, 256, 0, stream>>>(qkv, Vt);

    dim3 ga(SEQ / 128, NH, BATCH);
    attn_kernel<<<ga, 256, 0, stream>>>(Qb, Kb, Vt, attn_out);

    dim3 g2(NTOK / 128, DIM / 128);
    gemm_bt<0><<<g2, 256, 0, stream>>>(attn_out, wob, out, nullptr, NTOK, DIM, DIM);
}

// Round 5
// 928.106 us; speedup vs baseline: 1.3409x; 1.2268x over previous
//
#include <hip/hip_runtime.h>
#include <stdint.h>

typedef unsigned short ushort_t;
typedef short v8s __attribute__((ext_vector_type(8)));
typedef short v4s __attribute__((ext_vector_type(4)));
typedef float v4f __attribute__((ext_vector_type(4)));
typedef unsigned int uint32;

#define DIM   4096
#define NH    32
#define NKV   8
#define HD    128
#define SEQ   2048
#define BATCH 2
#define NTOK  (BATCH * SEQ)            // 4096 tokens
#define QKVN  (NH * HD + 2 * NKV * HD) // 6144 = 4096 Q + 1024 K + 1024 V
#define KOFF  (NH * HD)                // 4096
#define VOFF  (NH * HD + NKV * HD)     // 5120

__device__ __forceinline__ ushort_t f2bf(float f) {
    uint32 u = __float_as_uint(f);
    u += 0x7fff + ((u >> 16) & 1);   // RNE
    return (ushort_t)(u >> 16);
}
__device__ __forceinline__ float bf2f(ushort_t h) {
    return __uint_as_float(((uint32)h) << 16);
}
__device__ __forceinline__ void gl2lds16(const void* g, void* l) {
    __builtin_amdgcn_global_load_lds(
        (const __attribute__((address_space(1))) uint32*)g,
        (__attribute__((address_space(3))) uint32*)l, 16, 0, 0);
}
#if __has_builtin(__builtin_amdgcn_exp2f)
__device__ __forceinline__ float fast_exp2(float x) { return __builtin_amdgcn_exp2f(x); }
#else
__device__ __forceinline__ float fast_exp2(float x) { return exp2f(x); }
#endif

// 16x16x16 bf16 MFMA. __has_builtin for amdgcn builtins is 0 in the HOST pass,
// but the host pass still semantic-checks __global__ bodies -> stub must be
// __host__ __device__. Device pass picks the real builtin.
#if !defined(__HIP_DEVICE_COMPILE__)
__host__ __device__ static inline v4f MFMA_B16_K16(v4s a, v4s b, v4f c) {
    (void)a; (void)b; return c;  // host-pass stub, never executed
}
#elif __has_builtin(__builtin_amdgcn_mfma_f32_16x16x16_bf16)
#define MFMA_B16_K16(A, B, C) __builtin_amdgcn_mfma_f32_16x16x16_bf16(A, B, C, 0, 0, 0)
#elif __has_builtin(__builtin_amdgcn_mfma_f32_16x16x16bf16_1k)
#define MFMA_B16_K16(A, B, C) __builtin_amdgcn_mfma_f32_16x16x16bf16_1k(A, B, C, 0, 0, 0)
#else
#error "no 16x16x16 bf16 MFMA builtin on device"
#endif

// ---------------- fp32 -> bf16 convert (vectorized) ----------------
__global__ void cvt_f32_bf16(const float* __restrict__ src,
                             ushort_t* __restrict__ dst, int n4) {
    int i = blockIdx.x * blockDim.x + threadIdx.x;
    if (i >= n4) return;
    float4 v = ((const float4*)src)[i];
    uint32 lo = ((uint32)f2bf(v.y) << 16) | f2bf(v.x);
    uint32 hi = ((uint32)f2bf(v.w) << 16) | f2bf(v.z);
    ((uint2*)dst)[i] = make_uint2(lo, hi);
}

// ---------------- GEMM: C[M,N] = A[M,K] * B[N,K]^T (bf16 in, f32 acc) -------
// 128x128 tile, 256 thr (4 waves, each 64x64), BK=32, global_load_lds staging.
// XOR chunk swizzle keeps every 16-lane ds_read_b128 slice spread over all
// 8 bank quads (2-way = free).
template <int OUT_BF16>
__global__ __launch_bounds__(256) void gemm_bt(const ushort_t* __restrict__ A,
                                               const ushort_t* __restrict__ B,
                                               float* __restrict__ Cf,
                                               ushort_t* __restrict__ Cb,
                                               int M, int N, int K) {
    __shared__ ushort_t As[128 * 32];
    __shared__ ushort_t Bs[128 * 32];
    const int t = threadIdx.x;
    const int w = t >> 6, lane = t & 63;
    const int g8 = lane >> 4, l16 = lane & 15;
    const int wr = (w >> 1) * 64, wc = (w & 1) * 64;
    const int bm = blockIdx.x, bn = blockIdx.y;

    const ushort_t* Ab = A + (size_t)(bm * 128) * K;
    const ushort_t* Bb = B + (size_t)(bn * 128) * K;

    v4f acc[4][4];
    v4f z = {0.f, 0.f, 0.f, 0.f};
#pragma unroll
    for (int i = 0; i < 4; i++)
#pragma unroll
        for (int j = 0; j < 4; j++) acc[i][j] = z;

    for (int k0 = 0; k0 < K; k0 += 32) {
        __syncthreads();
#pragma unroll
        for (int i = 0; i < 2; ++i) {
            int c = i * 256 + t;             // physical chunk 0..511
            int p = c >> 3, low = c & 7;
            int l7 = low ^ (p & 7);
            int r = p * 2 + (l7 >> 2);
            int cc = l7 & 3;
            gl2lds16(&Ab[(size_t)r * K + k0 + cc * 8], &As[c * 8]);
            gl2lds16(&Bb[(size_t)r * K + k0 + cc * 8], &Bs[c * 8]);
        }
        __syncthreads();
        v8s a[4], b[4];
#pragma unroll
        for (int i = 0; i < 4; i++) {
            int R = wr + i * 16 + l16;
            int pc = (R >> 1) * 8 + ((((R & 1) << 2) | g8) ^ ((R >> 1) & 7));
            a[i] = *(const v8s*)&As[pc * 8];
        }
#pragma unroll
        for (int j = 0; j < 4; j++) {
            int R = wc + j * 16 + l16;
            int pc = (R >> 1) * 8 + ((((R & 1) << 2) | g8) ^ ((R >> 1) & 7));
            b[j] = *(const v8s*)&Bs[pc * 8];
        }
#pragma unroll
        for (int i = 0; i < 4; i++)
#pragma unroll
            for (int j = 0; j < 4; j++)
                acc[i][j] = __builtin_amdgcn_mfma_f32_16x16x32_bf16(
                    a[i], b[j], acc[i][j], 0, 0, 0);
    }

    const int rowbase = bm * 128 + wr, colbase = bn * 128 + wc;
#pragma unroll
    for (int i = 0; i < 4; i++)
#pragma unroll
        for (int j = 0; j < 4; j++)
#pragma unroll
            for (int r = 0; r < 4; r++) {
                int row = rowbase + i * 16 + g8 * 4 + r;
                int col = colbase + j * 16 + l16;
                float v = acc[i][j][r];
                if (OUT_BF16)
                    Cb[(size_t)row * N + col] = f2bf(v);
                else
                    Cf[(size_t)row * N + col] = v;
            }
}

// ---------------- RoPE + reorg: qkv[tok][6144] -> Q[b,h,s,d], K[b,g,s,d] ----
// Q pre-scaled by (1/sqrt(HD)) * log2(e): softmax runs in exp2 domain.
__global__ __launch_bounds__(256) void rope_reorg(const ushort_t* __restrict__ qkv,
                                                  const float* __restrict__ fc,
                                                  const float* __restrict__ fs,
                                                  ushort_t* __restrict__ Qo,
                                                  ushort_t* __restrict__ Ko) {
    const int tok = blockIdx.x;
    const int bb = tok >> 11, s = tok & 2047;
    const ushort_t* base = qkv + (size_t)tok * QKVN;
    const int t = threadIdx.x;
    const float qscale = 0.08838834764831845f * 1.4426950408889634f;
    uint32* Qw = (uint32*)Qo;
    uint32* Kw = (uint32*)Ko;
#pragma unroll
    for (int i = 0; i < 8; ++i) {
        int p = i * 256 + t;
        int hh = p >> 6, pi = p & 63;
        float c = fc[s * 64 + pi], sn = fs[s * 64 + pi];
        uint32 u = *(const uint32*)&base[hh * 128 + 2 * pi];
        float t0 = bf2f((ushort_t)(u & 0xffff));
        float t1 = bf2f((ushort_t)(u >> 16));
        float o0 = (t0 * c - t1 * sn) * qscale;
        float o1 = (t0 * sn + t1 * c) * qscale;
        size_t dst = (((size_t)bb * NH + hh) * SEQ + s) * HD + 2 * pi;
        Qw[dst >> 1] = ((uint32)f2bf(o1) << 16) | f2bf(o0);
    }
#pragma unroll
    for (int i = 0; i < 2; ++i) {
        int p = i * 256 + t;
        int hh = p >> 6, pi = p & 63;
        float c = fc[s * 64 + pi], sn = fs[s * 64 + pi];
        uint32 u = *(const uint32*)&base[KOFF + hh * 128 + 2 * pi];
        float t0 = bf2f((ushort_t)(u & 0xffff));
        float t1 = bf2f((ushort_t)(u >> 16));
        float o0 = t0 * c - t1 * sn;
        float o1 = t0 * sn + t1 * c;
        size_t dst = (((size_t)bb * NKV + hh) * SEQ + s) * HD + 2 * pi;
        Kw[dst >> 1] = ((uint32)f2bf(o1) << 16) | f2bf(o0);
    }
}

// ---------------- V transpose: qkv V slice -> Vt[b,g,d,s] -------------------
__global__ __launch_bounds__(256) void v_transpose(const ushort_t* __restrict__ qkv,
                                                   ushort_t* __restrict__ Vt) {
    __shared__ ushort_t tile[64][136];
    const int st = blockIdx.x, kvh = blockIdx.y, bb = blockIdx.z;
    const int t = threadIdx.x;
    const int s0 = st * 64;
#pragma unroll
    for (int i = 0; i < 4; ++i) {
        int c = i * 256 + t;
        int r = c >> 4, col8 = (c & 15) * 8;
        int tok = (bb << 11) + s0 + r;
        *(v8s*)&tile[r][col8] =
            *(const v8s*)&qkv[(size_t)tok * QKVN + VOFF + kvh * 128 + col8];
    }
    __syncthreads();
#pragma unroll
    for (int i = 0; i < 4; ++i) {
        int c = i * 256 + t;
        int d = c >> 3, s8 = (c & 7) * 8;
        ushort_t tmp[8];
#pragma unroll
        for (int j = 0; j < 8; j++) tmp[j] = tile[s8 + j][d];
        *(v8s*)&Vt[(((size_t)bb * NKV + kvh) * HD + d) * SEQ + s0 + s8] =
            *(v8s*)tmp;
    }
}

// ---------------- Flash attention (causal, GQA) -----------------------------
// Block: 64 q-rows, 4 waves, wave = 16 q-rows. S^T trick: S^T = mfma(kb, qf)
// puts one q-row per lane (q = lane&15) -> softmax reduction = per-lane VALU
// tree + 2 shfls, and S^T's C-layout IS the A-layout of the K=16 MFMA, so
// P feeds PV directly from registers (no LDS round trip).
__global__ __launch_bounds__(256, 4) void attn_kernel(const ushort_t* __restrict__ Q,
                                                      const ushort_t* __restrict__ Kc,
                                                      const ushort_t* __restrict__ Vt,
                                                      ushort_t* __restrict__ Out) {
    __shared__ ushort_t Ks[64 * 128];      // swizzled K tile [key][d]
    __shared__ ushort_t Vs[128 * 64];      // swizzled Vt tile [d][key]
    const int qtb = gridDim.x - 1 - blockIdx.x;  // heavy blocks first
    const int h = blockIdx.y, bb = blockIdx.z;
    const int kvh = h >> 2;
    const int t = threadIdx.x, w = t >> 6, lane = t & 63;
    const int g8 = lane >> 4, l16 = lane & 15;
    const int R = qtb * 64 + w * 16;       // wave q-tile base
    const int qrow = R + l16;              // this lane's softmax row

    const size_t qb = (((size_t)bb * NH + h) * SEQ + R) * HD;
    v8s qf[4];
#pragma unroll
    for (int ks = 0; ks < 4; ++ks)
        qf[ks] = *(const v8s*)&Q[qb + (size_t)l16 * HD + ks * 32 + g8 * 8];

    float m_i = -3.0e38f, l_i = 0.f;
    v4f z = {0.f, 0.f, 0.f, 0.f};
    v4f o[8];
#pragma unroll
    for (int n = 0; n < 8; n++) o[n] = z;

    const ushort_t* Kbase = Kc + ((size_t)bb * NKV + kvh) * SEQ * HD;
    const ushort_t* Vbase = Vt + ((size_t)bb * NKV + kvh) * HD * SEQ;

    const int nkt = qtb + 1;
    for (int kt = 0; kt < nkt; ++kt) {
        const int k0 = kt * 64;
        __syncthreads();
        const ushort_t* Kt = Kbase + (size_t)k0 * HD;
#pragma unroll
        for (int i = 0; i < 4; ++i) {   // K: 64 rows x 16 chunks, swizzled
            int c = i * 256 + t;
            int r = c >> 4, cc = (c & 15) ^ (r & 15);
            gl2lds16(&Kt[r * 128 + cc * 8], &Ks[c * 8]);
        }
#pragma unroll
        for (int i = 0; i < 4; ++i) {   // V: 128 d-rows x 8 chunks, swizzled
            int c = i * 256 + t;
            int d = c >> 3, cc = (c & 7) ^ (d & 7);
            gl2lds16(&Vbase[(size_t)d * SEQ + k0 + cc * 8], &Vs[c * 8]);
        }
        __syncthreads();

        // S^T tiles: j covers keys k0+j*16..+15; lane: q=l16, key=g8*4+r
        v4f s[4];
#pragma unroll
        for (int j = 0; j < 4; j++) s[j] = z;
#pragma unroll
        for (int j = 0; j < 4; j++)
#pragma unroll
            for (int ks = 0; ks < 4; ks++) {
                const v8s kb = *(const v8s*)&Ks[((j * 16 + l16) * 16 + ((ks * 4 + g8) ^ l16)) * 8];
                s[j] = __builtin_amdgcn_mfma_f32_16x16x32_bf16(kb, qf[ks], s[j], 0, 0, 0);
            }

        if (kt == nkt - 1) {  // diagonal tile: causal mask
#pragma unroll
            for (int j = 0; j < 4; j++)
#pragma unroll
                for (int r = 0; r < 4; r++) {
                    int key = k0 + j * 16 + g8 * 4 + r;
                    if (key > qrow) s[j][r] = -3.0e38f;
                }
        }

        // per-lane max over 16 + 2-shfl butterfly across the 4 g8 copies
        float mx = fmaxf(fmaxf(s[0][0], s[0][1]), fmaxf(s[0][2], s[0][3]));
#pragma unroll
        for (int j = 1; j < 4; j++)
            mx = fmaxf(mx, fmaxf(fmaxf(s[j][0], s[j][1]), fmaxf(s[j][2], s[j][3])));
        mx = fmaxf(mx, __shfl_xor(mx, 16, 64));
        mx = fmaxf(mx, __shfl_xor(mx, 32, 64));
        float mnew = fmaxf(m_i, mx);
        float alpha = fast_exp2(m_i - mnew);
        m_i = mnew;

        float sum = 0.f;
        v4s pj[4];
#pragma unroll
        for (int j = 0; j < 4; j++)
#pragma unroll
            for (int r = 0; r < 4; r++) {
                float p = fast_exp2(s[j][r] - m_i);
                sum += p;
                pj[j][r] = (short)f2bf(p);
            }
        sum += __shfl_xor(sum, 16, 64);
        sum += __shfl_xor(sum, 32, 64);
        l_i = l_i * alpha + sum;

        // O rescale: O C-layout rows are q=g8*4+r -> broadcast alpha from lanes 0-15
        float alo[4];
#pragma unroll
        for (int r = 0; r < 4; r++) alo[r] = __shfl(alpha, g8 * 4 + r, 64);
#pragma unroll
        for (int n = 0; n < 8; n++)
#pragma unroll
            for (int r = 0; r < 4; r++) o[n][r] *= alo[r];

        // O += P V via K=16 MFMA: A = pj (q x key), B = Vs rows (d), k=key
#pragma unroll
        for (int j = 0; j < 4; j++)
#pragma unroll
            for (int n = 0; n < 8; n++) {
                const int d = n * 16 + l16;
                const v4s vb = *(const v4s*)&Vs[d * 64 + (((j * 2 + (g8 >> 1)) ^ (l16 & 7)) * 8) + (g8 & 1) * 4];
                o[n] = MFMA_B16_K16(pj[j], vb, o[n]);
            }
    }

    // epilogue: Out[b][s][h][d]; O row g8*4+r = q, col l16 (+16n) = d
    float lo[4];
#pragma unroll
    for (int r = 0; r < 4; r++) lo[r] = __shfl(l_i, g8 * 4 + r, 64);
#pragma unroll
    for (int n = 0; n < 8; n++)
#pragma unroll
        for (int r = 0; r < 4; r++) {
            int row = R + g8 * 4 + r;
            int col = n * 16 + l16;
            Out[(((size_t)bb * SEQ + row) * NH + h) * HD + col] = f2bf(o[n][r] / lo[r]);
        }
}

// ---------------- launch ----------------------------------------------------
extern "C" void kernel_launch(void* const* d_in, const int* in_sizes, int n_in,
                              void* d_out, int out_size, void* d_ws, size_t ws_size,
                              hipStream_t stream) {
    const float* x  = (const float*)d_in[0];
    const float* wq = (const float*)d_in[1];
    const float* wk = (const float*)d_in[2];
    const float* wv = (const float*)d_in[3];
    const float* wo = (const float*)d_in[4];
    const float* fc = (const float*)d_in[5];
    const float* fs = (const float*)d_in[6];
    float* out = (float*)d_out;

    ushort_t* ws = (ushort_t*)d_ws;
    size_t off = 0;
    ushort_t* xb    = ws + off; off += (size_t)NTOK * DIM;   // reused as attn_out
    ushort_t* wqkvb = ws + off; off += (size_t)QKVN * DIM;
    ushort_t* wob   = ws + off; off += (size_t)DIM * DIM;
    ushort_t* qkv   = ws + off; off += (size_t)NTOK * QKVN;
    ushort_t* Qb    = ws + off; off += (size_t)BATCH * NH * SEQ * HD;
    ushort_t* Kb    = ws + off; off += (size_t)BATCH * NKV * SEQ * HD;
    ushort_t* Vt    = ws + off; off += (size_t)BATCH * NKV * HD * SEQ;
    ushort_t* attn_out = xb;  // x dead after QKV GEMM

    cvt_f32_bf16<<<(NTOK * DIM / 4) / 256, 256, 0, stream>>>(x, xb, NTOK * DIM / 4);
    cvt_f32_bf16<<<(DIM * DIM / 4) / 256, 256, 0, stream>>>(wq, wqkvb, DIM * DIM / 4);
    cvt_f32_bf16<<<(NKV * HD * DIM / 4) / 256, 256, 0, stream>>>(
        wk, wqkvb + (size_t)KOFF * DIM, NKV * HD * DIM / 4);
    cvt_f32_bf16<<<(NKV * HD * DIM / 4) / 256, 256, 0, stream>>>(
        wv, wqkvb + (size_t)VOFF * DIM, NKV * HD * DIM / 4);
    cvt_f32_bf16<<<(DIM * DIM / 4) / 256, 256, 0, stream>>>(wo, wob, DIM * DIM / 4);

    dim3 g1(NTOK / 128, QKVN / 128);
    gemm_bt<1><<<g1, 256, 0, stream>>>(xb, wqkvb, nullptr, qkv, NTOK, QKVN, DIM);

    rope_reorg<<<NTOK, 256, 0, stream>>>(qkv, fc, fs, Qb, Kb);
    dim3 gv(SEQ / 64, NKV, BATCH);
    v_transpose<<<gv, 256, 0, stream>>>(qkv, Vt);

    dim3 ga(SEQ / 64, NH, BATCH);
    attn_kernel<<<ga, 256, 0, stream>>>(Qb, Kb, Vt, attn_out);

    dim3 g2(NTOK / 128, DIM / 128);
    gemm_bt<0><<<g2, 256, 0, stream>>>(attn_out, wob, out, nullptr, NTOK, DIM, DIM);
}